// Round 1
// baseline (556.442 us; speedup 1.0000x reference)
//
#include <hip/hip_runtime.h>
#include <stdint.h>

typedef unsigned short u16;
typedef __attribute__((ext_vector_type(8))) short bf16x8;
typedef __attribute__((ext_vector_type(4))) float f32x4;
typedef __attribute__((ext_vector_type(4))) unsigned short u16x4;

#define DEVI static __device__ __forceinline__

// dots*scale folded into Q, with base-2 softmax: exp(s) == exp2(s*log2e)
#define QSCALE (0.125f * 1.4426950408889634f)

DEVI u16 f2bf(float f) {
  union { float f; unsigned int u; } v; v.f = f;
  unsigned int u = v.u + 0x7fffu + ((v.u >> 16) & 1u);
  return (u16)(u >> 16);
}
DEVI float bf2f(u16 h) {
  union { unsigned int u; float f; } v; v.u = ((unsigned int)h) << 16;
  return v.f;
}
DEVI void gl16(const void* g, void* l) {
  __builtin_amdgcn_global_load_lds(
      (__attribute__((address_space(1))) void*)g,
      (__attribute__((address_space(3))) void*)l, 16, 0, 0);
}

// ---------------- K1: LayerNorm + hi/lo split ----------------
__global__ __launch_bounds__(256) void k_ln_split(
    const float* __restrict__ x, const float* __restrict__ gamma,
    const float* __restrict__ beta, u16* __restrict__ xh, u16* __restrict__ xl) {
  const int row = blockIdx.x;          // 8192 rows
  const int t = threadIdx.x;           // 256 threads, 4 floats each
  const float4* xr = (const float4*)(x + (size_t)row * 1024);
  float4 v = xr[t];
  float s = v.x + v.y + v.z + v.w;
  float s2 = v.x * v.x + v.y * v.y + v.z * v.z + v.w * v.w;
  #pragma unroll
  for (int m = 1; m < 64; m <<= 1) { s += __shfl_xor(s, m); s2 += __shfl_xor(s2, m); }
  __shared__ float ls[4], ls2[4];
  if ((t & 63) == 0) { ls[t >> 6] = s; ls2[t >> 6] = s2; }
  __syncthreads();
  s = ls[0] + ls[1] + ls[2] + ls[3];
  s2 = ls2[0] + ls2[1] + ls2[2] + ls2[3];
  float mu = s * (1.0f / 1024.0f);
  float var = s2 * (1.0f / 1024.0f) - mu * mu;
  float rstd = rsqrtf(var + 1e-5f);
  float4 g = ((const float4*)gamma)[t];
  float4 b = ((const float4*)beta)[t];
  float xv[4] = {v.x, v.y, v.z, v.w};
  float gg[4] = {g.x, g.y, g.z, g.w};
  float bb[4] = {b.x, b.y, b.z, b.w};
  u16x4 hv, lv;
  #pragma unroll
  for (int i = 0; i < 4; i++) {
    float xn = (xv[i] - mu) * rstd * gg[i] + bb[i];
    u16 hi = f2bf(xn);
    hv[i] = hi; lv[i] = f2bf(xn - bf2f(hi));
  }
  ((u16x4*)xh)[(size_t)row * 256 + t] = hv;
  ((u16x4*)xl)[(size_t)row * 256 + t] = lv;
}

// ---------------- K1b: transpose + hi/lo split of weights ----------------
// W [K][N] fp32  ->  Wt hi/lo [N][K] bf16
__global__ __launch_bounds__(256) void k_wsplit_t(
    const float* __restrict__ W, u16* __restrict__ Wth, u16* __restrict__ Wtl,
    int K, int N) {
  __shared__ float tile[32][33];
  const int t = threadIdx.x;
  const int tx = t & 31, ty = t >> 5;  // ty in 0..7
  #pragma unroll
  for (int i = 0; i < 4; i++) {
    int k = blockIdx.y * 32 + ty + i * 8;
    int n = blockIdx.x * 32 + tx;
    tile[ty + i * 8][tx] = W[(size_t)k * N + n];
  }
  __syncthreads();
  #pragma unroll
  for (int i = 0; i < 4; i++) {
    int n = blockIdx.x * 32 + ty + i * 8;   // output row
    int k = blockIdx.y * 32 + tx;           // output col
    float v = tile[tx][ty + i * 8];
    size_t o = (size_t)n * K + k;
    u16 hi = f2bf(v);
    Wth[o] = hi; Wtl[o] = f2bf(v - bf2f(hi));
  }
}

// ---------------- K2/K4: split-precision GEMM (m97 structure) ----------------
// C[M x N] = A[M x 1024] * Bt[N x 1024]^T, with A,B as hi/lo bf16 pairs.
// MODE 0: QKV epilogue (scatter Q,K scaled, V transposed, all hi/lo)
// MODE 1: out-proj epilogue (+bias, fp32 store)
template <int MODE>
__global__ __launch_bounds__(256) void k_gemm(
    const u16* __restrict__ Ah, const u16* __restrict__ Al,
    const u16* __restrict__ Bh, const u16* __restrict__ Bl,
    u16* __restrict__ Qh, u16* __restrict__ Ql,
    u16* __restrict__ Kh, u16* __restrict__ Kl,
    u16* __restrict__ Vth, u16* __restrict__ Vtl,
    float* __restrict__ Cout, const float* __restrict__ bias) {
  __shared__ u16 sAh[128 * 32], sAl[128 * 32], sBh[128 * 32], sBl[128 * 32];
  const int t = threadIdx.x, lane = t & 63, w = t >> 6;
  const int bm = blockIdx.x, bn = blockIdx.y;
  const int wm = (w >> 1) * 64, wn = (w & 1) * 64;
  const int g = lane >> 4, c = lane & 15;
  const size_t arow0 = (size_t)bm * 128, brow0 = (size_t)bn * 128;

  f32x4 acc[4][4] = {};

  for (int kt = 0; kt < 32; kt++) {
    __syncthreads();
    #pragma unroll
    for (int i = 0; i < 2; i++) {
      int ci = t + i * 256;              // 512 chunks of 16B per tile
      int r = ci >> 2, cc = ci & 3;
      size_t ka = (size_t)kt * 32 + cc * 8;
      gl16(Ah + (arow0 + r) * 1024 + ka, sAh + (size_t)ci * 8);
      gl16(Al + (arow0 + r) * 1024 + ka, sAl + (size_t)ci * 8);
      gl16(Bh + (brow0 + r) * 1024 + ka, sBh + (size_t)ci * 8);
      gl16(Bl + (brow0 + r) * 1024 + ka, sBl + (size_t)ci * 8);
    }
    __syncthreads();
    bf16x8 afh[4], afl[4], bfh[4], bfl[4];
    #pragma unroll
    for (int mi = 0; mi < 4; mi++) {
      int off = (wm + mi * 16 + c) * 32 + g * 8;
      afh[mi] = *(const bf16x8*)(sAh + off);
      afl[mi] = *(const bf16x8*)(sAl + off);
    }
    #pragma unroll
    for (int ni = 0; ni < 4; ni++) {
      int off = (wn + ni * 16 + c) * 32 + g * 8;
      bfh[ni] = *(const bf16x8*)(sBh + off);
      bfl[ni] = *(const bf16x8*)(sBl + off);
    }
    #pragma unroll
    for (int mi = 0; mi < 4; mi++)
      #pragma unroll
      for (int ni = 0; ni < 4; ni++) {
        acc[mi][ni] = __builtin_amdgcn_mfma_f32_16x16x32_bf16(afh[mi], bfh[ni], acc[mi][ni], 0, 0, 0);
        acc[mi][ni] = __builtin_amdgcn_mfma_f32_16x16x32_bf16(afh[mi], bfl[ni], acc[mi][ni], 0, 0, 0);
        acc[mi][ni] = __builtin_amdgcn_mfma_f32_16x16x32_bf16(afl[mi], bfh[ni], acc[mi][ni], 0, 0, 0);
      }
  }

  if (MODE == 0) {
    #pragma unroll
    for (int mi = 0; mi < 4; mi++) {
      int grow0 = bm * 128 + wm + mi * 16 + g * 4;   // m = b*2048+s
      int b = grow0 >> 11, s0 = grow0 & 2047;
      #pragma unroll
      for (int ni = 0; ni < 4; ni++) {
        int gcol = bn * 128 + wn + ni * 16 + c;       // n in [0,3072)
        int which = gcol >> 10, rem = gcol & 1023;
        int hh = rem >> 6, dd = rem & 63;
        if (which == 2) {                              // V -> transposed [B,H,Dh,S]
          u16x4 hv, lv;
          #pragma unroll
          for (int r = 0; r < 4; r++) {
            float v = acc[mi][ni][r];
            u16 hi = f2bf(v);
            hv[r] = hi; lv[r] = f2bf(v - bf2f(hi));
          }
          size_t off = ((size_t)((b * 16 + hh) * 64 + dd)) * 2048 + s0;
          *(u16x4*)(Vth + off) = hv;
          *(u16x4*)(Vtl + off) = lv;
        } else {                                       // Q or K -> [B,H,S,Dh]
          u16* dh = which ? Kh : Qh;
          u16* dl = which ? Kl : Ql;
          float sc = which ? 1.0f : QSCALE;
          #pragma unroll
          for (int r = 0; r < 4; r++) {
            float v = acc[mi][ni][r] * sc;
            size_t off = ((size_t)(b * 16 + hh) * 2048 + (s0 + r)) * 64 + dd;
            u16 hi = f2bf(v);
            dh[off] = hi; dl[off] = f2bf(v - bf2f(hi));
          }
        }
      }
    }
  } else {
    #pragma unroll
    for (int mi = 0; mi < 4; mi++) {
      int grow0 = bm * 128 + wm + mi * 16 + g * 4;
      #pragma unroll
      for (int ni = 0; ni < 4; ni++) {
        int gcol = bn * 128 + wn + ni * 16 + c;
        float bb = bias[gcol];
        #pragma unroll
        for (int r = 0; r < 4; r++)
          Cout[(size_t)(grow0 + r) * 1024 + gcol] = acc[mi][ni][r] + bb;
      }
    }
  }
}

// ---------------- K3: block-causal flash attention ----------------
// grid (16 qtiles, 64 b*h); 4 waves x 32 q-rows; kv tiles of 64.
// TQ=128 lies inside one 256-window -> uniform kv_len, no masking.
__global__ __launch_bounds__(256) void k_attn(
    const u16* __restrict__ Qh, const u16* __restrict__ Ql,
    const u16* __restrict__ Kh, const u16* __restrict__ Kl,
    const u16* __restrict__ Vth, const u16* __restrict__ Vtl,
    u16* __restrict__ Oh, u16* __restrict__ Ol) {
  __shared__ u16 lKh[64 * 64], lKl[64 * 64], lVh[64 * 64], lVl[64 * 64]; // 8KB each
  __shared__ u16 lP[4 * 2048];                                           // 4 waves x [32][64]
  const int t = threadIdx.x, lane = t & 63, w = t >> 6;
  const int qt = blockIdx.x;             // 0..15
  const int bh = blockIdx.y;             // 0..63
  const int b = bh >> 4, h = bh & 15;
  const int qrow0 = qt * 128;
  const int kvlen = (qt / 2 + 1) * 256;
  const int g = lane >> 4, c = lane & 15;

  // Q fragments for this wave's 32 rows (hi/lo), k = Dh in two 32-steps
  bf16x8 qfh[2][2], qfl[2][2];
  {
    const u16* qb = Qh + ((size_t)bh * 2048 + qrow0 + w * 32) * 64;
    const u16* ql = Ql + ((size_t)bh * 2048 + qrow0 + w * 32) * 64;
    #pragma unroll
    for (int mi = 0; mi < 2; mi++)
      #pragma unroll
      for (int ks = 0; ks < 2; ks++) {
        size_t off = (size_t)(mi * 16 + c) * 64 + ks * 32 + g * 8;
        qfh[mi][ks] = *(const bf16x8*)(qb + off);
        qfl[mi][ks] = *(const bf16x8*)(ql + off);
      }
  }

  const u16* Kb = Kh + (size_t)bh * 2048 * 64;
  const u16* Klb = Kl + (size_t)bh * 2048 * 64;
  const u16* Vb = Vth + (size_t)bh * 64 * 2048;
  const u16* Vlb = Vtl + (size_t)bh * 64 * 2048;
  u16* pb = lP + w * 2048;

  float mrun[2][4], lrun[2][4];
  f32x4 o[2][4] = {};
  #pragma unroll
  for (int mi = 0; mi < 2; mi++)
    #pragma unroll
    for (int r = 0; r < 4; r++) { mrun[mi][r] = -INFINITY; lrun[mi][r] = 0.f; }

  const int ntiles = kvlen >> 6;
  for (int kt = 0; kt < ntiles; kt++) {
    const int kv0 = kt * 64;
    __syncthreads();
    // stage K hi/lo [64 kv][64 d] and Vt hi/lo [64 d][64 kv], source pre-swizzled
    #pragma unroll
    for (int i = 0; i < 2; i++) {
      int ci = t + i * 256;                 // 512 chunks per tile
      int r = ci >> 3, cc = ci & 7;
      int ccs = cc ^ (r & 7);
      gl16(Kb  + ((size_t)(kv0 + r)) * 64 + ccs * 8, lKh + (size_t)ci * 8);
      gl16(Klb + ((size_t)(kv0 + r)) * 64 + ccs * 8, lKl + (size_t)ci * 8);
      gl16(Vb  + (size_t)r * 2048 + kv0 + ccs * 8,   lVh + (size_t)ci * 8);
      gl16(Vlb + (size_t)r * 2048 + kv0 + ccs * 8,   lVl + (size_t)ci * 8);
    }
    __syncthreads();

    // scores: S[32 x 64] = Qs * K^T (split-precision, 3 products)
    f32x4 s[2][4] = {};
    #pragma unroll
    for (int ni = 0; ni < 4; ni++) {
      int kr = ni * 16 + c;
      #pragma unroll
      for (int ks = 0; ks < 2; ks++) {
        int ch = (ks * 4 + g) ^ (kr & 7);
        int off = kr * 64 + ch * 8;
        bf16x8 kh = *(const bf16x8*)(lKh + off);
        bf16x8 kl = *(const bf16x8*)(lKl + off);
        #pragma unroll
        for (int mi = 0; mi < 2; mi++) {
          s[mi][ni] = __builtin_amdgcn_mfma_f32_16x16x32_bf16(qfh[mi][ks], kh, s[mi][ni], 0, 0, 0);
          s[mi][ni] = __builtin_amdgcn_mfma_f32_16x16x32_bf16(qfh[mi][ks], kl, s[mi][ni], 0, 0, 0);
          s[mi][ni] = __builtin_amdgcn_mfma_f32_16x16x32_bf16(qfl[mi][ks], kh, s[mi][ni], 0, 0, 0);
        }
      }
    }

    // online softmax (base-2), rows live in 16-lane groups
    #pragma unroll
    for (int mi = 0; mi < 2; mi++)
      #pragma unroll
      for (int r = 0; r < 4; r++) {
        float tm = fmaxf(fmaxf(s[mi][0][r], s[mi][1][r]), fmaxf(s[mi][2][r], s[mi][3][r]));
        tm = fmaxf(tm, __shfl_xor(tm, 1));
        tm = fmaxf(tm, __shfl_xor(tm, 2));
        tm = fmaxf(tm, __shfl_xor(tm, 4));
        tm = fmaxf(tm, __shfl_xor(tm, 8));
        float mnew = fmaxf(mrun[mi][r], tm);
        float alpha = exp2f(mrun[mi][r] - mnew);
        float ps = 0.f;
        #pragma unroll
        for (int ni = 0; ni < 4; ni++) {
          float p = exp2f(s[mi][ni][r] - mnew);
          s[mi][ni][r] = p;
          ps += p;
        }
        ps += __shfl_xor(ps, 1); ps += __shfl_xor(ps, 2);
        ps += __shfl_xor(ps, 4); ps += __shfl_xor(ps, 8);
        lrun[mi][r] = lrun[mi][r] * alpha + ps;
        mrun[mi][r] = mnew;
        #pragma unroll
        for (int di = 0; di < 4; di++) o[mi][di][r] *= alpha;
      }

    // P -> wave-private LDS (bf16, XOR-swizzled both sides)
    #pragma unroll
    for (int mi = 0; mi < 2; mi++)
      #pragma unroll
      for (int ni = 0; ni < 4; ni++)
        #pragma unroll
        for (int r = 0; r < 4; r++) {
          int row = mi * 16 + g * 4 + r;
          int byteo = (row * 128 + (ni * 16 + c) * 2) ^ ((row & 7) << 4);
          *(u16*)((char*)pb + byteo) = f2bf(s[mi][ni][r]);
        }

    // PV: O += P * V (V hi/lo)
    bf16x8 pa[2][2];
    #pragma unroll
    for (int mi = 0; mi < 2; mi++)
      #pragma unroll
      for (int ks = 0; ks < 2; ks++) {
        int row = mi * 16 + c;
        int byteo = (row * 128 + (ks * 4 + g) * 16) ^ ((row & 7) << 4);
        pa[mi][ks] = *(const bf16x8*)((char*)pb + byteo);
      }
    #pragma unroll
    for (int di = 0; di < 4; di++) {
      int vr = di * 16 + c;
      #pragma unroll
      for (int ks = 0; ks < 2; ks++) {
        int ch = (ks * 4 + g) ^ (vr & 7);
        int off = vr * 64 + ch * 8;
        bf16x8 vh = *(const bf16x8*)(lVh + off);
        bf16x8 vl = *(const bf16x8*)(lVl + off);
        #pragma unroll
        for (int mi = 0; mi < 2; mi++) {
          o[mi][di] = __builtin_amdgcn_mfma_f32_16x16x32_bf16(pa[mi][ks], vh, o[mi][di], 0, 0, 0);
          o[mi][di] = __builtin_amdgcn_mfma_f32_16x16x32_bf16(pa[mi][ks], vl, o[mi][di], 0, 0, 0);
        }
      }
    }
  }

  // epilogue: normalize, hi/lo split, write attnout [B*S][1024]
  #pragma unroll
  for (int mi = 0; mi < 2; mi++)
    #pragma unroll
    for (int r = 0; r < 4; r++) {
      float inv = 1.0f / lrun[mi][r];
      int srow = qrow0 + w * 32 + mi * 16 + g * 4 + r;
      size_t rowo = ((size_t)b * 2048 + srow) * 1024 + h * 64;
      #pragma unroll
      for (int di = 0; di < 4; di++) {
        float v = o[mi][di][r] * inv;
        u16 hi = f2bf(v);
        Oh[rowo + di * 16 + c] = hi;
        Ol[rowo + di * 16 + c] = f2bf(v - bf2f(hi));
      }
    }
}

// ---------------- launch ----------------
extern "C" void kernel_launch(void* const* d_in, const int* in_sizes, int n_in,
                              void* d_out, int out_size, void* d_ws, size_t ws_size,
                              hipStream_t stream) {
  const float* x     = (const float*)d_in[0];
  const float* gamma = (const float*)d_in[1];
  const float* beta  = (const float*)d_in[2];
  const float* Wqkv  = (const float*)d_in[3];
  const float* Wout  = (const float*)d_in[4];
  const float* bout  = (const float*)d_in[5];
  float* out = (float*)d_out;

  char* ws = (char*)d_ws;
  size_t off = 0;
  auto alloc = [&](size_t bytes) { char* p = ws + off; off += (bytes + 255) & ~(size_t)255; return p; };
  const size_t SZ_XN = (size_t)8192 * 1024 * 2;      // 16MB
  const size_t SZ_WQ = (size_t)3072 * 1024 * 2;      // 6MB
  const size_t SZ_WO = (size_t)1024 * 1024 * 2;      // 2MB
  const size_t SZ_QKV = (size_t)4 * 16 * 2048 * 64 * 2; // 16MB
  u16* xnh  = (u16*)alloc(SZ_XN);
  u16* xnl  = (u16*)alloc(SZ_XN);
  u16* wqth = (u16*)alloc(SZ_WQ);
  u16* wqtl = (u16*)alloc(SZ_WQ);
  u16* woth = (u16*)alloc(SZ_WO);
  u16* wotl = (u16*)alloc(SZ_WO);
  u16* Qh = (u16*)alloc(SZ_QKV);
  u16* Ql = (u16*)alloc(SZ_QKV);
  u16* Kh = (u16*)alloc(SZ_QKV);
  u16* Kl = (u16*)alloc(SZ_QKV);
  u16* Vth = (u16*)alloc(SZ_QKV);
  u16* Vtl = (u16*)alloc(SZ_QKV);
  if (off > ws_size) return;  // workspace too small -> fail visibly (poisoned out)

  k_ln_split<<<8192, 256, 0, stream>>>(x, gamma, beta, xnh, xnl);
  k_wsplit_t<<<dim3(96, 32), 256, 0, stream>>>(Wqkv, wqth, wqtl, 1024, 3072);
  k_wsplit_t<<<dim3(32, 32), 256, 0, stream>>>(Wout, woth, wotl, 1024, 1024);
  k_gemm<0><<<dim3(64, 24), 256, 0, stream>>>(xnh, xnl, wqth, wqtl,
                                              Qh, Ql, Kh, Kl, Vth, Vtl,
                                              nullptr, nullptr);
  // attnout (hi/lo) reuses the xn buffers (xn is dead after the QKV GEMM)
  k_attn<<<dim3(16, 64), 256, 0, stream>>>(Qh, Ql, Kh, Kl, Vth, Vtl, xnh, xnl);
  k_gemm<1><<<dim3(64, 8), 256, 0, stream>>>(xnh, xnl, woth, wotl,
                                             nullptr, nullptr, nullptr, nullptr, nullptr, nullptr,
                                             out, bout);
}

// Round 2
// 400.528 us; speedup vs baseline: 1.3893x; 1.3893x over previous
//
#include <hip/hip_runtime.h>
#include <stdint.h>

typedef unsigned short u16;
typedef __attribute__((ext_vector_type(8))) short bf16x8;
typedef __attribute__((ext_vector_type(4))) float f32x4;
typedef __attribute__((ext_vector_type(4))) unsigned short u16x4;

#define DEVI static __device__ __forceinline__

// dots*scale folded into Q, with base-2 softmax: exp(s) == exp2(s*log2e)
#define QSCALE (0.125f * 1.4426950408889634f)

DEVI u16 f2bf(float f) {
  union { float f; unsigned int u; } v; v.f = f;
  unsigned int u = v.u + 0x7fffu + ((v.u >> 16) & 1u);
  return (u16)(u >> 16);
}
DEVI float bf2f(u16 h) {
  union { unsigned int u; float f; } v; v.u = ((unsigned int)h) << 16;
  return v.f;
}
DEVI void gl16(const void* g, void* l) {
  __builtin_amdgcn_global_load_lds(
      (__attribute__((address_space(1))) void*)g,
      (__attribute__((address_space(3))) void*)l, 16, 0, 0);
}

// ---------------- K1: LayerNorm + hi/lo split ----------------
__global__ __launch_bounds__(256) void k_ln_split(
    const float* __restrict__ x, const float* __restrict__ gamma,
    const float* __restrict__ beta, u16* __restrict__ xh, u16* __restrict__ xl) {
  const int row = blockIdx.x;          // 8192 rows
  const int t = threadIdx.x;           // 256 threads, 4 floats each
  const float4* xr = (const float4*)(x + (size_t)row * 1024);
  float4 v = xr[t];
  float s = v.x + v.y + v.z + v.w;
  float s2 = v.x * v.x + v.y * v.y + v.z * v.z + v.w * v.w;
  #pragma unroll
  for (int m = 1; m < 64; m <<= 1) { s += __shfl_xor(s, m); s2 += __shfl_xor(s2, m); }
  __shared__ float ls[4], ls2[4];
  if ((t & 63) == 0) { ls[t >> 6] = s; ls2[t >> 6] = s2; }
  __syncthreads();
  s = ls[0] + ls[1] + ls[2] + ls[3];
  s2 = ls2[0] + ls2[1] + ls2[2] + ls2[3];
  float mu = s * (1.0f / 1024.0f);
  float var = s2 * (1.0f / 1024.0f) - mu * mu;
  float rstd = rsqrtf(var + 1e-5f);
  float4 g = ((const float4*)gamma)[t];
  float4 b = ((const float4*)beta)[t];
  float xv[4] = {v.x, v.y, v.z, v.w};
  float gg[4] = {g.x, g.y, g.z, g.w};
  float bb[4] = {b.x, b.y, b.z, b.w};
  u16x4 hv, lv;
  #pragma unroll
  for (int i = 0; i < 4; i++) {
    float xn = (xv[i] - mu) * rstd * gg[i] + bb[i];
    u16 hi = f2bf(xn);
    hv[i] = hi; lv[i] = f2bf(xn - bf2f(hi));
  }
  ((u16x4*)xh)[(size_t)row * 256 + t] = hv;
  ((u16x4*)xl)[(size_t)row * 256 + t] = lv;
}

// ---------------- K1b: transpose + hi/lo split of weights ----------------
// W [K][N] fp32  ->  Wt hi/lo [N][K] bf16
__global__ __launch_bounds__(256) void k_wsplit_t(
    const float* __restrict__ W, u16* __restrict__ Wth, u16* __restrict__ Wtl,
    int K, int N) {
  __shared__ float tile[32][33];
  const int t = threadIdx.x;
  const int tx = t & 31, ty = t >> 5;  // ty in 0..7
  #pragma unroll
  for (int i = 0; i < 4; i++) {
    int k = blockIdx.y * 32 + ty + i * 8;
    int n = blockIdx.x * 32 + tx;
    tile[ty + i * 8][tx] = W[(size_t)k * N + n];
  }
  __syncthreads();
  #pragma unroll
  for (int i = 0; i < 4; i++) {
    int n = blockIdx.x * 32 + ty + i * 8;   // output row
    int k = blockIdx.y * 32 + tx;           // output col
    float v = tile[tx][ty + i * 8];
    size_t o = (size_t)n * K + k;
    u16 hi = f2bf(v);
    Wth[o] = hi; Wtl[o] = f2bf(v - bf2f(hi));
  }
}

// ---------------- K2/K4: split-precision GEMM (m97 structure) ----------------
// C[M x N] = A[M x 1024] * Bt[N x 1024]^T, with A,B as hi/lo bf16 pairs.
// MODE 0: QKV epilogue (scatter Q,K scaled, V transposed, all hi/lo)
// MODE 1: out-proj epilogue (+bias, fp32 store)
template <int MODE>
__global__ __launch_bounds__(256) void k_gemm(
    const u16* __restrict__ Ah, const u16* __restrict__ Al,
    const u16* __restrict__ Bh, const u16* __restrict__ Bl,
    u16* __restrict__ Qh, u16* __restrict__ Ql,
    u16* __restrict__ Kh, u16* __restrict__ Kl,
    u16* __restrict__ Vth, u16* __restrict__ Vtl,
    float* __restrict__ Cout, const float* __restrict__ bias) {
  __shared__ u16 sAh[128 * 32], sAl[128 * 32], sBh[128 * 32], sBl[128 * 32];
  const int t = threadIdx.x, lane = t & 63, w = t >> 6;
  const int bm = blockIdx.x, bn = blockIdx.y;
  const int wm = (w >> 1) * 64, wn = (w & 1) * 64;
  const int g = lane >> 4, c = lane & 15;
  const size_t arow0 = (size_t)bm * 128, brow0 = (size_t)bn * 128;

  f32x4 acc[4][4] = {};

  for (int kt = 0; kt < 32; kt++) {
    __syncthreads();
    #pragma unroll
    for (int i = 0; i < 2; i++) {
      int ci = t + i * 256;              // 512 chunks of 16B per tile
      int r = ci >> 2, cc = ci & 3;
      size_t ka = (size_t)kt * 32 + cc * 8;
      gl16(Ah + (arow0 + r) * 1024 + ka, sAh + (size_t)ci * 8);
      gl16(Al + (arow0 + r) * 1024 + ka, sAl + (size_t)ci * 8);
      gl16(Bh + (brow0 + r) * 1024 + ka, sBh + (size_t)ci * 8);
      gl16(Bl + (brow0 + r) * 1024 + ka, sBl + (size_t)ci * 8);
    }
    __syncthreads();
    bf16x8 afh[4], afl[4], bfh[4], bfl[4];
    #pragma unroll
    for (int mi = 0; mi < 4; mi++) {
      int off = (wm + mi * 16 + c) * 32 + g * 8;
      afh[mi] = *(const bf16x8*)(sAh + off);
      afl[mi] = *(const bf16x8*)(sAl + off);
    }
    #pragma unroll
    for (int ni = 0; ni < 4; ni++) {
      int off = (wn + ni * 16 + c) * 32 + g * 8;
      bfh[ni] = *(const bf16x8*)(sBh + off);
      bfl[ni] = *(const bf16x8*)(sBl + off);
    }
    #pragma unroll
    for (int mi = 0; mi < 4; mi++)
      #pragma unroll
      for (int ni = 0; ni < 4; ni++) {
        acc[mi][ni] = __builtin_amdgcn_mfma_f32_16x16x32_bf16(afh[mi], bfh[ni], acc[mi][ni], 0, 0, 0);
        acc[mi][ni] = __builtin_amdgcn_mfma_f32_16x16x32_bf16(afh[mi], bfl[ni], acc[mi][ni], 0, 0, 0);
        acc[mi][ni] = __builtin_amdgcn_mfma_f32_16x16x32_bf16(afl[mi], bfh[ni], acc[mi][ni], 0, 0, 0);
      }
  }

  if (MODE == 0) {
    #pragma unroll
    for (int mi = 0; mi < 4; mi++) {
      int grow0 = bm * 128 + wm + mi * 16 + g * 4;   // m = b*2048+s
      int b = grow0 >> 11, s0 = grow0 & 2047;
      #pragma unroll
      for (int ni = 0; ni < 4; ni++) {
        int gcol = bn * 128 + wn + ni * 16 + c;       // n in [0,3072)
        int which = gcol >> 10, rem = gcol & 1023;
        int hh = rem >> 6, dd = rem & 63;
        if (which == 2) {                              // V -> transposed [B,H,Dh,S]
          u16x4 hv, lv;
          #pragma unroll
          for (int r = 0; r < 4; r++) {
            float v = acc[mi][ni][r];
            u16 hi = f2bf(v);
            hv[r] = hi; lv[r] = f2bf(v - bf2f(hi));
          }
          size_t off = ((size_t)((b * 16 + hh) * 64 + dd)) * 2048 + s0;
          *(u16x4*)(Vth + off) = hv;
          *(u16x4*)(Vtl + off) = lv;
        } else {                                       // Q or K -> [B,H,S,Dh]
          u16* dh = which ? Kh : Qh;
          u16* dl = which ? Kl : Ql;
          float sc = which ? 1.0f : QSCALE;
          #pragma unroll
          for (int r = 0; r < 4; r++) {
            float v = acc[mi][ni][r] * sc;
            size_t off = ((size_t)(b * 16 + hh) * 2048 + (s0 + r)) * 64 + dd;
            u16 hi = f2bf(v);
            dh[off] = hi; dl[off] = f2bf(v - bf2f(hi));
          }
        }
      }
    }
  } else {
    #pragma unroll
    for (int mi = 0; mi < 4; mi++) {
      int grow0 = bm * 128 + wm + mi * 16 + g * 4;
      #pragma unroll
      for (int ni = 0; ni < 4; ni++) {
        int gcol = bn * 128 + wn + ni * 16 + c;
        float bb = bias[gcol];
        #pragma unroll
        for (int r = 0; r < 4; r++)
          Cout[(size_t)(grow0 + r) * 1024 + gcol] = acc[mi][ni][r] + bb;
      }
    }
  }
}

// ---------------- K3: block-causal flash attention (v2) ----------------
// grid (64 b*h, 16 qtiles desc); 4 waves x 32 q-rows; kv tiles of 64.
// Double-buffered staging: issue next tile's global_load_lds before computing
// the current tile, so the barrier's vmcnt(0) drain lands after ~1k cycles of
// MFMA+softmax. LDS: 4 streams x 2 bufs x 8KB + P 16KB = 80KB -> 2 blocks/CU.
__global__ __launch_bounds__(256) void k_attn(
    const u16* __restrict__ Qh, const u16* __restrict__ Ql,
    const u16* __restrict__ Kh, const u16* __restrict__ Kl,
    const u16* __restrict__ Vth, const u16* __restrict__ Vtl,
    u16* __restrict__ Oh, u16* __restrict__ Ol) {
  __shared__ u16 lKh[2][64 * 64], lKl[2][64 * 64];
  __shared__ u16 lVh[2][64 * 64], lVl[2][64 * 64];
  __shared__ u16 lP[4 * 2048];                        // 4 waves x [32][64]
  const int t = threadIdx.x, lane = t & 63, w = t >> 6;
  const int bh = blockIdx.x;             // 0..63
  const int qt = 15 - blockIdx.y;        // longest blocks dispatched first
  const int b = bh >> 4, h = bh & 15;
  const int qrow0 = qt * 128;
  const int kvlen = (qt / 2 + 1) * 256;
  const int g = lane >> 4, c = lane & 15;

  // Q fragments for this wave's 32 rows (hi/lo), k = Dh in two 32-steps
  bf16x8 qfh[2][2], qfl[2][2];
  {
    const u16* qb = Qh + ((size_t)bh * 2048 + qrow0 + w * 32) * 64;
    const u16* ql = Ql + ((size_t)bh * 2048 + qrow0 + w * 32) * 64;
    #pragma unroll
    for (int mi = 0; mi < 2; mi++)
      #pragma unroll
      for (int ks = 0; ks < 2; ks++) {
        size_t off = (size_t)(mi * 16 + c) * 64 + ks * 32 + g * 8;
        qfh[mi][ks] = *(const bf16x8*)(qb + off);
        qfl[mi][ks] = *(const bf16x8*)(ql + off);
      }
  }

  const u16* Kb = Kh + (size_t)bh * 2048 * 64;
  const u16* Klb = Kl + (size_t)bh * 2048 * 64;
  const u16* Vb = Vth + (size_t)bh * 64 * 2048;
  const u16* Vlb = Vtl + (size_t)bh * 64 * 2048;
  u16* pb = lP + w * 2048;

  // staging helper: K hi/lo [64 kv][64 d] and Vt hi/lo [64 d][64 kv],
  // source pre-swizzled (XOR by row) so the linear LDS write lands swizzled.
  const int ci0 = t, ci1 = t + 256;
  const int r0 = ci0 >> 3, cc0 = ci0 & 7;
  const int r1 = ci1 >> 3, cc1 = ci1 & 7;
  const int cs0 = cc0 ^ (r0 & 7), cs1 = cc1 ^ (r1 & 7);

  float mrun[2][4], lrun[2][4];
  f32x4 o[2][4] = {};
  #pragma unroll
  for (int mi = 0; mi < 2; mi++)
    #pragma unroll
    for (int r = 0; r < 4; r++) { mrun[mi][r] = -INFINITY; lrun[mi][r] = 0.f; }

  const int ntiles = kvlen >> 6;

  // prologue: stage tile 0 into buffer 0
  {
    gl16(Kb  + (size_t)r0 * 64 + cs0 * 8, lKh[0] + (size_t)ci0 * 8);
    gl16(Klb + (size_t)r0 * 64 + cs0 * 8, lKl[0] + (size_t)ci0 * 8);
    gl16(Vb  + (size_t)r0 * 2048 + cs0 * 8, lVh[0] + (size_t)ci0 * 8);
    gl16(Vlb + (size_t)r0 * 2048 + cs0 * 8, lVl[0] + (size_t)ci0 * 8);
    gl16(Kb  + (size_t)r1 * 64 + cs1 * 8, lKh[0] + (size_t)ci1 * 8);
    gl16(Klb + (size_t)r1 * 64 + cs1 * 8, lKl[0] + (size_t)ci1 * 8);
    gl16(Vb  + (size_t)r1 * 2048 + cs1 * 8, lVh[0] + (size_t)ci1 * 8);
    gl16(Vlb + (size_t)r1 * 2048 + cs1 * 8, lVl[0] + (size_t)ci1 * 8);
  }
  __syncthreads();

  for (int kt = 0; kt < ntiles; kt++) {
    const int cur = kt & 1, nxt = cur ^ 1;
    // prefetch next tile (in flight across the whole compute phase)
    if (kt + 1 < ntiles) {
      const size_t kv0 = (size_t)(kt + 1) * 64;
      gl16(Kb  + (kv0 + r0) * 64 + cs0 * 8, lKh[nxt] + (size_t)ci0 * 8);
      gl16(Klb + (kv0 + r0) * 64 + cs0 * 8, lKl[nxt] + (size_t)ci0 * 8);
      gl16(Vb  + (size_t)r0 * 2048 + kv0 + cs0 * 8, lVh[nxt] + (size_t)ci0 * 8);
      gl16(Vlb + (size_t)r0 * 2048 + kv0 + cs0 * 8, lVl[nxt] + (size_t)ci0 * 8);
      gl16(Kb  + (kv0 + r1) * 64 + cs1 * 8, lKh[nxt] + (size_t)ci1 * 8);
      gl16(Klb + (kv0 + r1) * 64 + cs1 * 8, lKl[nxt] + (size_t)ci1 * 8);
      gl16(Vb  + (size_t)r1 * 2048 + kv0 + cs1 * 8, lVh[nxt] + (size_t)ci1 * 8);
      gl16(Vlb + (size_t)r1 * 2048 + kv0 + cs1 * 8, lVl[nxt] + (size_t)ci1 * 8);
    }

    // scores: S[32 x 64] = Qs * K^T (split-precision, 3 products)
    f32x4 s[2][4] = {};
    #pragma unroll
    for (int ni = 0; ni < 4; ni++) {
      int kr = ni * 16 + c;
      #pragma unroll
      for (int ks = 0; ks < 2; ks++) {
        int ch = (ks * 4 + g) ^ (kr & 7);
        int off = kr * 64 + ch * 8;
        bf16x8 kh = *(const bf16x8*)(lKh[cur] + off);
        bf16x8 kl = *(const bf16x8*)(lKl[cur] + off);
        #pragma unroll
        for (int mi = 0; mi < 2; mi++) {
          s[mi][ni] = __builtin_amdgcn_mfma_f32_16x16x32_bf16(qfh[mi][ks], kh, s[mi][ni], 0, 0, 0);
          s[mi][ni] = __builtin_amdgcn_mfma_f32_16x16x32_bf16(qfh[mi][ks], kl, s[mi][ni], 0, 0, 0);
          s[mi][ni] = __builtin_amdgcn_mfma_f32_16x16x32_bf16(qfl[mi][ks], kh, s[mi][ni], 0, 0, 0);
        }
      }
    }

    // online softmax (base-2), batched so the 8 independent row-chains
    // overlap their shfl latencies
    float tm[2][4], al[2][4], ps[2][4];
    #pragma unroll
    for (int mi = 0; mi < 2; mi++)
      #pragma unroll
      for (int r = 0; r < 4; r++)
        tm[mi][r] = fmaxf(fmaxf(s[mi][0][r], s[mi][1][r]), fmaxf(s[mi][2][r], s[mi][3][r]));
    #pragma unroll
    for (int m = 1; m < 16; m <<= 1)
      #pragma unroll
      for (int mi = 0; mi < 2; mi++)
        #pragma unroll
        for (int r = 0; r < 4; r++)
          tm[mi][r] = fmaxf(tm[mi][r], __shfl_xor(tm[mi][r], m));
    #pragma unroll
    for (int mi = 0; mi < 2; mi++)
      #pragma unroll
      for (int r = 0; r < 4; r++) {
        float mnew = fmaxf(mrun[mi][r], tm[mi][r]);
        al[mi][r] = exp2f(mrun[mi][r] - mnew);
        mrun[mi][r] = mnew;
      }
    #pragma unroll
    for (int mi = 0; mi < 2; mi++)
      #pragma unroll
      for (int ni = 0; ni < 4; ni++)
        #pragma unroll
        for (int r = 0; r < 4; r++)
          s[mi][ni][r] = exp2f(s[mi][ni][r] - mrun[mi][r]);
    #pragma unroll
    for (int mi = 0; mi < 2; mi++)
      #pragma unroll
      for (int r = 0; r < 4; r++)
        ps[mi][r] = (s[mi][0][r] + s[mi][1][r]) + (s[mi][2][r] + s[mi][3][r]);
    #pragma unroll
    for (int m = 1; m < 16; m <<= 1)
      #pragma unroll
      for (int mi = 0; mi < 2; mi++)
        #pragma unroll
        for (int r = 0; r < 4; r++)
          ps[mi][r] += __shfl_xor(ps[mi][r], m);
    #pragma unroll
    for (int mi = 0; mi < 2; mi++)
      #pragma unroll
      for (int r = 0; r < 4; r++)
        lrun[mi][r] = lrun[mi][r] * al[mi][r] + ps[mi][r];
    #pragma unroll
    for (int mi = 0; mi < 2; mi++)
      #pragma unroll
      for (int di = 0; di < 4; di++)
        #pragma unroll
        for (int r = 0; r < 4; r++)
          o[mi][di][r] *= al[mi][r];

    // P -> wave-private LDS (bf16, XOR-swizzled both sides)
    #pragma unroll
    for (int mi = 0; mi < 2; mi++)
      #pragma unroll
      for (int ni = 0; ni < 4; ni++)
        #pragma unroll
        for (int r = 0; r < 4; r++) {
          int row = mi * 16 + g * 4 + r;
          int byteo = (row * 128 + (ni * 16 + c) * 2) ^ ((row & 7) << 4);
          *(u16*)((char*)pb + byteo) = f2bf(s[mi][ni][r]);
        }

    // PV: O += P * V (V hi/lo)
    bf16x8 pa[2][2];
    #pragma unroll
    for (int mi = 0; mi < 2; mi++)
      #pragma unroll
      for (int ks = 0; ks < 2; ks++) {
        int row = mi * 16 + c;
        int byteo = (row * 128 + (ks * 4 + g) * 16) ^ ((row & 7) << 4);
        pa[mi][ks] = *(const bf16x8*)((char*)pb + byteo);
      }
    #pragma unroll
    for (int di = 0; di < 4; di++) {
      int vr = di * 16 + c;
      #pragma unroll
      for (int ks = 0; ks < 2; ks++) {
        int ch = (ks * 4 + g) ^ (vr & 7);
        int off = vr * 64 + ch * 8;
        bf16x8 vh = *(const bf16x8*)(lVh[cur] + off);
        bf16x8 vl = *(const bf16x8*)(lVl[cur] + off);
        #pragma unroll
        for (int mi = 0; mi < 2; mi++) {
          o[mi][di] = __builtin_amdgcn_mfma_f32_16x16x32_bf16(pa[mi][ks], vh, o[mi][di], 0, 0, 0);
          o[mi][di] = __builtin_amdgcn_mfma_f32_16x16x32_bf16(pa[mi][ks], vl, o[mi][di], 0, 0, 0);
        }
      }
    }

    // drains the prefetch (issued ~1k cycles ago) and fences buffer reuse + lP
    __syncthreads();
  }

  // epilogue: normalize, hi/lo split, write attnout [B*S][1024]
  #pragma unroll
  for (int mi = 0; mi < 2; mi++)
    #pragma unroll
    for (int r = 0; r < 4; r++) {
      float inv = 1.0f / lrun[mi][r];
      int srow = qrow0 + w * 32 + mi * 16 + g * 4 + r;
      size_t rowo = ((size_t)b * 2048 + srow) * 1024 + h * 64;
      #pragma unroll
      for (int di = 0; di < 4; di++) {
        float v = o[mi][di][r] * inv;
        u16 hi = f2bf(v);
        Oh[rowo + di * 16 + c] = hi;
        Ol[rowo + di * 16 + c] = f2bf(v - bf2f(hi));
      }
    }
}

// ---------------- launch ----------------
extern "C" void kernel_launch(void* const* d_in, const int* in_sizes, int n_in,
                              void* d_out, int out_size, void* d_ws, size_t ws_size,
                              hipStream_t stream) {
  const float* x     = (const float*)d_in[0];
  const float* gamma = (const float*)d_in[1];
  const float* beta  = (const float*)d_in[2];
  const float* Wqkv  = (const float*)d_in[3];
  const float* Wout  = (const float*)d_in[4];
  const float* bout  = (const float*)d_in[5];
  float* out = (float*)d_out;

  char* ws = (char*)d_ws;
  size_t off = 0;
  auto alloc = [&](size_t bytes) { char* p = ws + off; off += (bytes + 255) & ~(size_t)255; return p; };
  const size_t SZ_XN = (size_t)8192 * 1024 * 2;      // 16MB
  const size_t SZ_WQ = (size_t)3072 * 1024 * 2;      // 6MB
  const size_t SZ_WO = (size_t)1024 * 1024 * 2;      // 2MB
  const size_t SZ_QKV = (size_t)4 * 16 * 2048 * 64 * 2; // 16MB
  u16* xnh  = (u16*)alloc(SZ_XN);
  u16* xnl  = (u16*)alloc(SZ_XN);
  u16* wqth = (u16*)alloc(SZ_WQ);
  u16* wqtl = (u16*)alloc(SZ_WQ);
  u16* woth = (u16*)alloc(SZ_WO);
  u16* wotl = (u16*)alloc(SZ_WO);
  u16* Qh = (u16*)alloc(SZ_QKV);
  u16* Ql = (u16*)alloc(SZ_QKV);
  u16* Kh = (u16*)alloc(SZ_QKV);
  u16* Kl = (u16*)alloc(SZ_QKV);
  u16* Vth = (u16*)alloc(SZ_QKV);
  u16* Vtl = (u16*)alloc(SZ_QKV);
  if (off > ws_size) return;  // workspace too small -> fail visibly (poisoned out)

  k_ln_split<<<8192, 256, 0, stream>>>(x, gamma, beta, xnh, xnl);
  k_wsplit_t<<<dim3(96, 32), 256, 0, stream>>>(Wqkv, wqth, wqtl, 1024, 3072);
  k_wsplit_t<<<dim3(32, 32), 256, 0, stream>>>(Wout, woth, wotl, 1024, 1024);
  k_gemm<0><<<dim3(64, 24), 256, 0, stream>>>(xnh, xnl, wqth, wqtl,
                                              Qh, Ql, Kh, Kl, Vth, Vtl,
                                              nullptr, nullptr);
  // attnout (hi/lo) reuses the xn buffers (xn is dead after the QKV GEMM)
  k_attn<<<dim3(64, 16), 256, 0, stream>>>(Qh, Ql, Kh, Kl, Vth, Vtl, xnh, xnl);
  k_gemm<1><<<dim3(64, 8), 256, 0, stream>>>(xnh, xnl, woth, wotl,
                                             nullptr, nullptr, nullptr, nullptr, nullptr, nullptr,
                                             out, bout);
}

// Round 3
// 309.094 us; speedup vs baseline: 1.8002x; 1.2958x over previous
//
#include <hip/hip_runtime.h>
#include <stdint.h>

typedef unsigned short u16;
typedef __attribute__((ext_vector_type(8))) short bf16x8;
typedef __attribute__((ext_vector_type(4))) float f32x4;
typedef __attribute__((ext_vector_type(4))) unsigned short u16x4;

#define DEVI static __device__ __forceinline__

// dots*scale folded into Q, with base-2 softmax: exp(s) == exp2(s*log2e)
#define QSCALE (0.125f * 1.4426950408889634f)

DEVI u16 f2bf(float f) {
  union { float f; unsigned int u; } v; v.f = f;
  unsigned int u = v.u + 0x7fffu + ((v.u >> 16) & 1u);
  return (u16)(u >> 16);
}
DEVI float bf2f(u16 h) {
  union { unsigned int u; float f; } v; v.u = ((unsigned int)h) << 16;
  return v.f;
}
DEVI void gl16(const void* g, void* l) {
  __builtin_amdgcn_global_load_lds(
      (__attribute__((address_space(1))) void*)g,
      (__attribute__((address_space(3))) void*)l, 16, 0, 0);
}
// packed f32x2 -> bf16x2 (RNE), lo=bf16(a), hi=bf16(b)
DEVI unsigned int cvtpk(float a, float b) {
  unsigned int r;
  asm("v_cvt_pk_bf16_f32 %0, %1, %2" : "=v"(r) : "v"(a), "v"(b));
  return r;
}

// ---------------- K1: LayerNorm (hi only; QKV GEMM is 2-product) ----------------
__global__ __launch_bounds__(256) void k_ln_split(
    const float* __restrict__ x, const float* __restrict__ gamma,
    const float* __restrict__ beta, u16* __restrict__ xh) {
  const int row = blockIdx.x;          // 8192 rows
  const int t = threadIdx.x;           // 256 threads, 4 floats each
  const float4* xr = (const float4*)(x + (size_t)row * 1024);
  float4 v = xr[t];
  float s = v.x + v.y + v.z + v.w;
  float s2 = v.x * v.x + v.y * v.y + v.z * v.z + v.w * v.w;
  #pragma unroll
  for (int m = 1; m < 64; m <<= 1) { s += __shfl_xor(s, m); s2 += __shfl_xor(s2, m); }
  __shared__ float ls[4], ls2[4];
  if ((t & 63) == 0) { ls[t >> 6] = s; ls2[t >> 6] = s2; }
  __syncthreads();
  s = ls[0] + ls[1] + ls[2] + ls[3];
  s2 = ls2[0] + ls2[1] + ls2[2] + ls2[3];
  float mu = s * (1.0f / 1024.0f);
  float var = s2 * (1.0f / 1024.0f) - mu * mu;
  float rstd = rsqrtf(var + 1e-5f);
  float4 g = ((const float4*)gamma)[t];
  float4 b = ((const float4*)beta)[t];
  float xv[4] = {v.x, v.y, v.z, v.w};
  float gg[4] = {g.x, g.y, g.z, g.w};
  float bb[4] = {b.x, b.y, b.z, b.w};
  u16x4 hv;
  #pragma unroll
  for (int i = 0; i < 4; i++) {
    float xn = (xv[i] - mu) * rstd * gg[i] + bb[i];
    hv[i] = f2bf(xn);
  }
  ((u16x4*)xh)[(size_t)row * 256 + t] = hv;
}

// ---------------- K1b: transpose + hi/lo split of weights ----------------
// W [K][N] fp32  ->  Wt hi/lo [N][K] bf16
__global__ __launch_bounds__(256) void k_wsplit_t(
    const float* __restrict__ W, u16* __restrict__ Wth, u16* __restrict__ Wtl,
    int K, int N) {
  __shared__ float tile[32][33];
  const int t = threadIdx.x;
  const int tx = t & 31, ty = t >> 5;  // ty in 0..7
  #pragma unroll
  for (int i = 0; i < 4; i++) {
    int k = blockIdx.y * 32 + ty + i * 8;
    int n = blockIdx.x * 32 + tx;
    tile[ty + i * 8][tx] = W[(size_t)k * N + n];
  }
  __syncthreads();
  #pragma unroll
  for (int i = 0; i < 4; i++) {
    int n = blockIdx.x * 32 + ty + i * 8;   // output row
    int k = blockIdx.y * 32 + tx;           // output col
    float v = tile[tx][ty + i * 8];
    size_t o = (size_t)n * K + k;
    u16 hi = f2bf(v);
    Wth[o] = hi; Wtl[o] = f2bf(v - bf2f(hi));
  }
}

// ---------------- K2/K4: GEMM (m97 structure) ----------------
// C[M x N] = A[M x 1024] * Bt[N x 1024]^T.
// MODE 0: A hi only, B hi/lo (2 products). Epilogue scatters Q(scaled),K,Vt bf16.
// MODE 1: A hi/lo, B hi/lo (3 products). Epilogue +bias, fp32 store.
template <int MODE>
__global__ __launch_bounds__(256) void k_gemm(
    const u16* __restrict__ Ah, const u16* __restrict__ Al,
    const u16* __restrict__ Bh, const u16* __restrict__ Bl,
    u16* __restrict__ Qh, u16* __restrict__ Kh, u16* __restrict__ Vth,
    float* __restrict__ Cout, const float* __restrict__ bias) {
  __shared__ u16 sAh[128 * 32], sBh[128 * 32], sBl[128 * 32];
  __shared__ u16 sAl[MODE == 1 ? 128 * 32 : 1];
  const int t = threadIdx.x, lane = t & 63, w = t >> 6;
  const int bm = blockIdx.x, bn = blockIdx.y;
  const int wm = (w >> 1) * 64, wn = (w & 1) * 64;
  const int g = lane >> 4, c = lane & 15;
  const size_t arow0 = (size_t)bm * 128, brow0 = (size_t)bn * 128;

  f32x4 acc[4][4] = {};

  for (int kt = 0; kt < 32; kt++) {
    __syncthreads();
    #pragma unroll
    for (int i = 0; i < 2; i++) {
      int ci = t + i * 256;              // 512 chunks of 16B per tile
      int r = ci >> 2, cc = ci & 3;
      size_t ka = (size_t)kt * 32 + cc * 8;
      gl16(Ah + (arow0 + r) * 1024 + ka, sAh + (size_t)ci * 8);
      gl16(Bh + (brow0 + r) * 1024 + ka, sBh + (size_t)ci * 8);
      gl16(Bl + (brow0 + r) * 1024 + ka, sBl + (size_t)ci * 8);
      if (MODE == 1) gl16(Al + (arow0 + r) * 1024 + ka, sAl + (size_t)ci * 8);
    }
    __syncthreads();
    bf16x8 afh[4], afl[4], bfh[4], bfl[4];
    #pragma unroll
    for (int mi = 0; mi < 4; mi++) {
      int off = (wm + mi * 16 + c) * 32 + g * 8;
      afh[mi] = *(const bf16x8*)(sAh + off);
      if (MODE == 1) afl[mi] = *(const bf16x8*)(sAl + off);
    }
    #pragma unroll
    for (int ni = 0; ni < 4; ni++) {
      int off = (wn + ni * 16 + c) * 32 + g * 8;
      bfh[ni] = *(const bf16x8*)(sBh + off);
      bfl[ni] = *(const bf16x8*)(sBl + off);
    }
    #pragma unroll
    for (int mi = 0; mi < 4; mi++)
      #pragma unroll
      for (int ni = 0; ni < 4; ni++) {
        acc[mi][ni] = __builtin_amdgcn_mfma_f32_16x16x32_bf16(afh[mi], bfh[ni], acc[mi][ni], 0, 0, 0);
        acc[mi][ni] = __builtin_amdgcn_mfma_f32_16x16x32_bf16(afh[mi], bfl[ni], acc[mi][ni], 0, 0, 0);
        if (MODE == 1)
          acc[mi][ni] = __builtin_amdgcn_mfma_f32_16x16x32_bf16(afl[mi], bfh[ni], acc[mi][ni], 0, 0, 0);
      }
  }

  if (MODE == 0) {
    #pragma unroll
    for (int mi = 0; mi < 4; mi++) {
      int grow0 = bm * 128 + wm + mi * 16 + g * 4;   // m = b*2048+s
      int b = grow0 >> 11, s0 = grow0 & 2047;
      #pragma unroll
      for (int ni = 0; ni < 4; ni++) {
        int gcol = bn * 128 + wn + ni * 16 + c;       // n in [0,3072)
        int which = gcol >> 10, rem = gcol & 1023;
        int hh = rem >> 6, dd = rem & 63;
        if (which == 2) {                              // V -> transposed [B,H,Dh,S]
          u16x4 hv;
          #pragma unroll
          for (int r = 0; r < 4; r++) hv[r] = f2bf(acc[mi][ni][r]);
          size_t off = ((size_t)((b * 16 + hh) * 64 + dd)) * 2048 + s0;
          *(u16x4*)(Vth + off) = hv;
        } else {                                       // Q or K -> [B,H,S,Dh]
          u16* dh = which ? Kh : Qh;
          float sc = which ? 1.0f : QSCALE;
          #pragma unroll
          for (int r = 0; r < 4; r++) {
            size_t off = ((size_t)(b * 16 + hh) * 2048 + (s0 + r)) * 64 + dd;
            dh[off] = f2bf(acc[mi][ni][r] * sc);
          }
        }
      }
    }
  } else {
    #pragma unroll
    for (int mi = 0; mi < 4; mi++) {
      int grow0 = bm * 128 + wm + mi * 16 + g * 4;
      #pragma unroll
      for (int ni = 0; ni < 4; ni++) {
        int gcol = bn * 128 + wn + ni * 16 + c;
        float bb = bias[gcol];
        #pragma unroll
        for (int r = 0; r < 4; r++)
          Cout[(size_t)(grow0 + r) * 1024 + gcol] = acc[mi][ni][r] + bb;
      }
    }
  }
}

// ---------------- K3: block-causal flash attention (v3, single bf16) ----------------
// grid (64 b*h, 16 qtiles desc); 4 waves x 32 q-rows; kv tiles of 64.
// Double-buffered K/V staging; defer-max rescale; cvt_pk P-store.
// LDS: K 2x8KB + V 2x8KB + P 16KB = 48KB -> 3 blocks/CU.
__global__ __launch_bounds__(256) void k_attn(
    const u16* __restrict__ Qh, const u16* __restrict__ Kh,
    const u16* __restrict__ Vth,
    u16* __restrict__ Oh, u16* __restrict__ Ol) {
  __shared__ u16 lK[2][64 * 64], lV[2][64 * 64];
  __shared__ u16 lP[4 * 2048];                        // 4 waves x [32][64]
  const int t = threadIdx.x, lane = t & 63, w = t >> 6;
  const int bh = blockIdx.x;             // 0..63
  const int qt = 15 - blockIdx.y;        // longest blocks dispatched first
  const int b = bh >> 4, h = bh & 15;
  const int qrow0 = qt * 128;
  const int kvlen = (qt / 2 + 1) * 256;
  const int g = lane >> 4, c = lane & 15;

  // Q fragments for this wave's 32 rows, k = Dh in two 32-steps
  bf16x8 qf[2][2];
  {
    const u16* qb = Qh + ((size_t)bh * 2048 + qrow0 + w * 32) * 64;
    #pragma unroll
    for (int mi = 0; mi < 2; mi++)
      #pragma unroll
      for (int ks = 0; ks < 2; ks++)
        qf[mi][ks] = *(const bf16x8*)(qb + (size_t)(mi * 16 + c) * 64 + ks * 32 + g * 8);
  }

  const u16* Kb = Kh + (size_t)bh * 2048 * 64;
  const u16* Vb = Vth + (size_t)bh * 64 * 2048;
  u16* pb = lP + w * 2048;

  // staging: K [64 kv][64 d], Vt [64 d][64 kv]; source pre-swizzled (XOR by row)
  const int ci0 = t, ci1 = t + 256;
  const int r0 = ci0 >> 3, cc0 = ci0 & 7;
  const int r1 = ci1 >> 3, cc1 = ci1 & 7;
  const int cs0 = cc0 ^ (r0 & 7), cs1 = cc1 ^ (r1 & 7);

  float mrun[2][4], lrun[2][4];
  f32x4 o[2][4] = {};
  #pragma unroll
  for (int mi = 0; mi < 2; mi++)
    #pragma unroll
    for (int r = 0; r < 4; r++) { mrun[mi][r] = -INFINITY; lrun[mi][r] = 0.f; }

  const int ntiles = kvlen >> 6;

  // prologue: stage tile 0 into buffer 0
  gl16(Kb + (size_t)r0 * 64 + cs0 * 8, lK[0] + (size_t)ci0 * 8);
  gl16(Vb + (size_t)r0 * 2048 + cs0 * 8, lV[0] + (size_t)ci0 * 8);
  gl16(Kb + (size_t)r1 * 64 + cs1 * 8, lK[0] + (size_t)ci1 * 8);
  gl16(Vb + (size_t)r1 * 2048 + cs1 * 8, lV[0] + (size_t)ci1 * 8);
  __syncthreads();

  for (int kt = 0; kt < ntiles; kt++) {
    const int cur = kt & 1, nxt = cur ^ 1;
    if (kt + 1 < ntiles) {               // prefetch next tile across compute
      const size_t kv0 = (size_t)(kt + 1) * 64;
      gl16(Kb + (kv0 + r0) * 64 + cs0 * 8, lK[nxt] + (size_t)ci0 * 8);
      gl16(Vb + (size_t)r0 * 2048 + kv0 + cs0 * 8, lV[nxt] + (size_t)ci0 * 8);
      gl16(Kb + (kv0 + r1) * 64 + cs1 * 8, lK[nxt] + (size_t)ci1 * 8);
      gl16(Vb + (size_t)r1 * 2048 + kv0 + cs1 * 8, lV[nxt] + (size_t)ci1 * 8);
    }

    // scores: S[32 x 64] = Qs * K^T
    f32x4 s[2][4] = {};
    __builtin_amdgcn_s_setprio(1);
    #pragma unroll
    for (int ni = 0; ni < 4; ni++) {
      int kr = ni * 16 + c;
      #pragma unroll
      for (int ks = 0; ks < 2; ks++) {
        int off = kr * 64 + ((ks * 4 + g) ^ (kr & 7)) * 8;
        bf16x8 kf = *(const bf16x8*)(lK[cur] + off);
        #pragma unroll
        for (int mi = 0; mi < 2; mi++)
          s[mi][ni] = __builtin_amdgcn_mfma_f32_16x16x32_bf16(qf[mi][ks], kf, s[mi][ni], 0, 0, 0);
      }
    }
    __builtin_amdgcn_s_setprio(0);

    // online softmax (base-2), batched row-chains; defer-max rescale (T13)
    float tm[2][4];
    #pragma unroll
    for (int mi = 0; mi < 2; mi++)
      #pragma unroll
      for (int r = 0; r < 4; r++)
        tm[mi][r] = fmaxf(fmaxf(s[mi][0][r], s[mi][1][r]), fmaxf(s[mi][2][r], s[mi][3][r]));
    #pragma unroll
    for (int m = 1; m < 16; m <<= 1)
      #pragma unroll
      for (int mi = 0; mi < 2; mi++)
        #pragma unroll
        for (int r = 0; r < 4; r++)
          tm[mi][r] = fmaxf(tm[mi][r], __shfl_xor(tm[mi][r], m));
    float dmax = -INFINITY;
    #pragma unroll
    for (int mi = 0; mi < 2; mi++)
      #pragma unroll
      for (int r = 0; r < 4; r++)
        dmax = fmaxf(dmax, tm[mi][r] - mrun[mi][r]);
    if (!__all(dmax <= 8.0f)) {
      #pragma unroll
      for (int mi = 0; mi < 2; mi++)
        #pragma unroll
        for (int r = 0; r < 4; r++) {
          float mnew = fmaxf(mrun[mi][r], tm[mi][r]);
          float al = exp2f(mrun[mi][r] - mnew);
          mrun[mi][r] = mnew;
          lrun[mi][r] *= al;
          #pragma unroll
          for (int di = 0; di < 4; di++) o[mi][di][r] *= al;
        }
    }
    #pragma unroll
    for (int mi = 0; mi < 2; mi++)
      #pragma unroll
      for (int ni = 0; ni < 4; ni++)
        #pragma unroll
        for (int r = 0; r < 4; r++)
          s[mi][ni][r] = exp2f(s[mi][ni][r] - mrun[mi][r]);
    float ps[2][4];
    #pragma unroll
    for (int mi = 0; mi < 2; mi++)
      #pragma unroll
      for (int r = 0; r < 4; r++)
        ps[mi][r] = (s[mi][0][r] + s[mi][1][r]) + (s[mi][2][r] + s[mi][3][r]);
    #pragma unroll
    for (int m = 1; m < 16; m <<= 1)
      #pragma unroll
      for (int mi = 0; mi < 2; mi++)
        #pragma unroll
        for (int r = 0; r < 4; r++)
          ps[mi][r] += __shfl_xor(ps[mi][r], m);
    #pragma unroll
    for (int mi = 0; mi < 2; mi++)
      #pragma unroll
      for (int r = 0; r < 4; r++)
        lrun[mi][r] += ps[mi][r];

    // P -> wave-private LDS (bf16 via cvt_pk, XOR-swizzled both sides)
    #pragma unroll
    for (int mi = 0; mi < 2; mi++)
      #pragma unroll
      for (int ni = 0; ni < 4; ni++)
        #pragma unroll
        for (int rp = 0; rp < 2; rp++) {
          unsigned int pk = cvtpk(s[mi][ni][2 * rp], s[mi][ni][2 * rp + 1]);
          int row0 = mi * 16 + g * 4 + 2 * rp;
          int colb = (ni * 16 + c) * 2;
          *(u16*)((char*)pb + ((row0 * 128 + colb) ^ ((row0 & 7) << 4))) = (u16)pk;
          *(u16*)((char*)pb + (((row0 + 1) * 128 + colb) ^ (((row0 + 1) & 7) << 4))) = (u16)(pk >> 16);
        }

    // PV: O += P * V
    bf16x8 pa[2][2];
    #pragma unroll
    for (int mi = 0; mi < 2; mi++)
      #pragma unroll
      for (int ks = 0; ks < 2; ks++) {
        int row = mi * 16 + c;
        pa[mi][ks] = *(const bf16x8*)((char*)pb + ((row * 128 + (ks * 4 + g) * 16) ^ ((row & 7) << 4)));
      }
    __builtin_amdgcn_s_setprio(1);
    #pragma unroll
    for (int di = 0; di < 4; di++) {
      int vr = di * 16 + c;
      #pragma unroll
      for (int ks = 0; ks < 2; ks++) {
        int off = vr * 64 + ((ks * 4 + g) ^ (vr & 7)) * 8;
        bf16x8 vf = *(const bf16x8*)(lV[cur] + off);
        #pragma unroll
        for (int mi = 0; mi < 2; mi++)
          o[mi][di] = __builtin_amdgcn_mfma_f32_16x16x32_bf16(pa[mi][ks], vf, o[mi][di], 0, 0, 0);
      }
    }
    __builtin_amdgcn_s_setprio(0);

    // drains the prefetch (issued ~1k cycles ago) and fences buffer reuse + lP
    __syncthreads();
  }

  // epilogue: normalize, hi/lo split, write attnout [B*S][1024]
  #pragma unroll
  for (int mi = 0; mi < 2; mi++)
    #pragma unroll
    for (int r = 0; r < 4; r++) {
      float inv = 1.0f / lrun[mi][r];
      int srow = qrow0 + w * 32 + mi * 16 + g * 4 + r;
      size_t rowo = ((size_t)b * 2048 + srow) * 1024 + h * 64;
      #pragma unroll
      for (int di = 0; di < 4; di++) {
        float v = o[mi][di][r] * inv;
        u16 hi = f2bf(v);
        Oh[rowo + di * 16 + c] = hi;
        Ol[rowo + di * 16 + c] = f2bf(v - bf2f(hi));
      }
    }
}

// ---------------- launch ----------------
extern "C" void kernel_launch(void* const* d_in, const int* in_sizes, int n_in,
                              void* d_out, int out_size, void* d_ws, size_t ws_size,
                              hipStream_t stream) {
  const float* x     = (const float*)d_in[0];
  const float* gamma = (const float*)d_in[1];
  const float* beta  = (const float*)d_in[2];
  const float* Wqkv  = (const float*)d_in[3];
  const float* Wout  = (const float*)d_in[4];
  const float* bout  = (const float*)d_in[5];
  float* out = (float*)d_out;

  char* ws = (char*)d_ws;
  size_t off = 0;
  auto alloc = [&](size_t bytes) { char* p = ws + off; off += (bytes + 255) & ~(size_t)255; return p; };
  const size_t SZ_XN = (size_t)8192 * 1024 * 2;         // 16MB
  const size_t SZ_WQ = (size_t)3072 * 1024 * 2;         // 6MB
  const size_t SZ_WO = (size_t)1024 * 1024 * 2;         // 2MB
  const size_t SZ_QKV = (size_t)4 * 16 * 2048 * 64 * 2; // 16MB
  u16* xnh  = (u16*)alloc(SZ_XN);   // also attnout-hi after attention
  u16* xnl  = (u16*)alloc(SZ_XN);   // attnout-lo (written by k_attn)
  u16* wqth = (u16*)alloc(SZ_WQ);
  u16* wqtl = (u16*)alloc(SZ_WQ);
  u16* woth = (u16*)alloc(SZ_WO);
  u16* wotl = (u16*)alloc(SZ_WO);
  u16* Qh  = (u16*)alloc(SZ_QKV);
  u16* Kh  = (u16*)alloc(SZ_QKV);
  u16* Vth = (u16*)alloc(SZ_QKV);
  if (off > ws_size) return;  // workspace too small -> fail visibly (poisoned out)

  k_ln_split<<<8192, 256, 0, stream>>>(x, gamma, beta, xnh);
  k_wsplit_t<<<dim3(96, 32), 256, 0, stream>>>(Wqkv, wqth, wqtl, 1024, 3072);
  k_wsplit_t<<<dim3(32, 32), 256, 0, stream>>>(Wout, woth, wotl, 1024, 1024);
  k_gemm<0><<<dim3(64, 24), 256, 0, stream>>>(xnh, nullptr, wqth, wqtl,
                                              Qh, Kh, Vth, nullptr, nullptr);
  // attnout (hi/lo) reuses the xn buffers (xn is dead after the QKV GEMM)
  k_attn<<<dim3(64, 16), 256, 0, stream>>>(Qh, Kh, Vth, xnh, xnl);
  k_gemm<1><<<dim3(64, 8), 256, 0, stream>>>(xnh, xnl, woth, wotl,
                                             nullptr, nullptr, nullptr,
                                             out, bout);
}